// Round 9
// baseline (1146.400 us; speedup 1.0000x reference)
//
#include <hip/hip_runtime.h>

#define NLIT 8192
#define NCLS 16384
#define DD 64
#define CCAP 64
#define LCAP 64

__device__ __forceinline__ float leaky(float x){ return x >= 0.f ? x : 0.01f*x; }

__device__ __forceinline__ float bf2f(unsigned short u){
  union { unsigned u; float f; } c; c.u = ((unsigned)u) << 16; return c.f;
}
__device__ __forceinline__ unsigned short f2bf(float f){
  union { float f; unsigned u; } c; c.f = f;
  unsigned b = c.u + 0x7fffu + ((c.u >> 16) & 1u);   // RNE
  return (unsigned short)(b >> 16);
}

// ---- fused: extract sparse lists from A  +  Lmsg linear (bf16, batch-interleaved) ----
// LmsgT2 layout: [lit][b][d] bf16 -> 512 B per literal row
__global__ __launch_bounds__(256) void extract_lmsg_k(const uint4* __restrict__ A4,
    int* __restrict__ ccnt, int* __restrict__ clist,
    int* __restrict__ lcnt, int* __restrict__ llist,
    const float* __restrict__ L, const float* __restrict__ W,
    const float* __restrict__ bias, unsigned short* __restrict__ LmsgT2){
  if (blockIdx.x < 16384){
    const int T = 16384*256;
    int tid = blockIdx.x*256 + threadIdx.x;
    uint4 v[8];
    #pragma unroll
    for (int u=0;u<8;u++) v[u] = A4[tid + (size_t)u*T];
    #pragma unroll
    for (int u=0;u<8;u++){
      if (v[u].x | v[u].y | v[u].z | v[u].w){
        int i = tid + u*T;
        int c = i >> 11;
        int l = (i & 2047) << 2;
        unsigned vv[4] = {v[u].x, v[u].y, v[u].z, v[u].w};
        #pragma unroll
        for (int j=0;j<4;j++){
          if (vv[j]){
            int p = atomicAdd(&ccnt[c],1);
            if (p < CCAP) clist[c*CCAP+p] = l+j;
            int q = atomicAdd(&lcnt[l+j],1);
            if (q < LCAP) llist[(l+j)*LCAP+q] = c;
          }
        }
      }
    }
  } else {
    __shared__ float X[64][65];
    __shared__ float Y[64][65];
    int bid = blockIdx.x - 16384;     // 0..511
    int b   = bid >> 7;
    int l0  = (bid & 127) << 6;
    int lane = threadIdx.x & 63;
    int wg = __builtin_amdgcn_readfirstlane(threadIdx.x >> 6);
    const float* Lb = L + (size_t)b*DD*NLIT;
    #pragma unroll
    for (int r=0;r<16;r++){
      int i = wg + 4*r;
      X[lane][i] = Lb[(size_t)i*NLIT + l0 + lane];
    }
    __syncthreads();
    float acc[16];
    #pragma unroll
    for (int j=0;j<16;j++) acc[j] = bias[wg*16+j];
    #pragma unroll 4
    for (int i=0;i<64;i++){
      float x = X[lane][i];
      #pragma unroll
      for (int j=0;j<16;j++) acc[j] += W[(wg*16+j)*64+i] * x;
    }
    #pragma unroll
    for (int j=0;j<16;j++) Y[lane][wg*16+j] = acc[j];
    __syncthreads();
    // write [lit][b][d]
    #pragma unroll
    for (int r=0;r<16;r++){
      int cc = wg + 4*r;
      LmsgT2[(size_t)(l0+cc)*256 + b*64 + lane] = f2bf(Y[cc][lane]);
    }
  }
}

// ---- clause side: block = 32 clauses x ALL 4 batches, 512 threads ----
// gather reads LmsgT2 rows (512 B = all batches of one literal) in ONE wave-load
__global__ __launch_bounds__(512) void clause_k(const float* __restrict__ Ct,
    const unsigned short* __restrict__ LmsgT2, const int* __restrict__ ccnt,
    const int* __restrict__ clist,
    const float* __restrict__ W_Cu, const float* __restrict__ b_Cu,
    const float* __restrict__ W_Cmsg, const float* __restrict__ b_Cmsg,
    unsigned short* __restrict__ CmsgT2, float* __restrict__ outC){
  __shared__ float SA[4][64][33];          // C_t / later C_new   [b][i][cl]
  __shared__ unsigned short SB[4][32][66]; // gathered msg bf16   [b][cl][i]
  int c0 = blockIdx.x << 5;
  int lane = threadIdx.x & 63;
  int w = __builtin_amdgcn_readfirstlane(threadIdx.x >> 6);   // 0..7
  // stage C_t: 256 rows (b,i) of 32 floats; wave w covers rows w*32..w*32+31
  #pragma unroll
  for (int it=0; it<16; it++){
    int row = w*32 + it*2 + (lane>>5);
    int b = row >> 6, i = row & 63;
    SA[b][i][lane&31] = Ct[((size_t)b*64 + i)*NCLS + c0 + (lane&31)];
  }
  // gather: wave w owns clauses w*4..w*4+3, 4 chains interleaved
  {
    int kk[4], rT[4];
    #pragma unroll
    for (int t=0;t<4;t++){
      int k = ccnt[c0 + w*4 + t];
      kk[t] = k > CCAP ? CCAP : k;
      rT[t] = (kk[t]+3) >> 2;
    }
    int Rm = max(max(rT[0],rT[1]),max(rT[2],rT[3]));
    float4 acc[4];
    #pragma unroll
    for (int t=0;t<4;t++) acc[t] = make_float4(0.f,0.f,0.f,0.f);
    for (int r=0;r<Rm;r++){
      #pragma unroll
      for (int t=0;t<4;t++){
        if (r < rT[t]){
          int4 li = *(const int4*)&clist[(c0 + w*4 + t)*CCAP + 4*r];
          int idx[4] = {li.x, li.y, li.z, li.w};
          #pragma unroll
          for (int e=0;e<4;e++){
            if (4*r+e < kk[t]){
              ushort4 x = *(const ushort4*)&LmsgT2[(size_t)idx[e]*256 + 4*lane];
              acc[t].x += bf2f(x.x); acc[t].y += bf2f(x.y);
              acc[t].z += bf2f(x.z); acc[t].w += bf2f(x.w);
            }
          }
        }
      }
    }
    int b = lane >> 4, h = lane & 15;
    #pragma unroll
    for (int t=0;t<4;t++){
      SB[b][w*4+t][4*h+0] = f2bf(acc[t].x);
      SB[b][w*4+t][4*h+1] = f2bf(acc[t].y);
      SB[b][w*4+t][4*h+2] = f2bf(acc[t].z);
      SB[b][w*4+t][4*h+3] = f2bf(acc[t].w);
    }
  }
  __syncthreads();
  // MLP1: thread -> (b = w>>1, half = w&1, cl = lane&31, sub = lane>>5), 16 outputs
  int b = w >> 1, half = w & 1, cl = lane & 31, sub = lane >> 5;
  float acc[16];
  {
    int ob = half*32 + sub*16;
    #pragma unroll
    for (int j=0;j<16;j++) acc[j] = b_Cu[ob+j];
    #pragma unroll 4
    for (int i=0;i<64;i++){
      float xa = SA[b][i][cl];
      float xm = bf2f(SB[b][cl][i]);
      #pragma unroll
      for (int j=0;j<16;j++){
        int o = ob + j;
        acc[j] += W_Cu[o*128+i]*xa + W_Cu[o*128+64+i]*xm;
      }
    }
    #pragma unroll
    for (int j=0;j<16;j++) acc[j] = leaky(acc[j]);
    float* oC = outC + (size_t)b*DD*NCLS;
    #pragma unroll
    for (int j=0;j<16;j++) oC[(size_t)(ob+j)*NCLS + c0 + cl] = acc[j];
  }
  __syncthreads();
  // stage C_new into SA  [b][o][cl]
  {
    int ob = half*32 + sub*16;
    #pragma unroll
    for (int j=0;j<16;j++) SA[b][ob+j][cl] = acc[j];
  }
  __syncthreads();
  // MLP2: Cmsg = W_Cmsg @ C_new + b
  float acc2[16];
  {
    int ob = half*32 + sub*16;
    #pragma unroll
    for (int j=0;j<16;j++) acc2[j] = b_Cmsg[ob+j];
    #pragma unroll 4
    for (int i=0;i<64;i++){
      float x = SA[b][i][cl];
      #pragma unroll
      for (int j=0;j<16;j++) acc2[j] += W_Cmsg[(ob+j)*64+i]*x;
    }
    // stage to SB [b][cl][o] for coalesced batch-interleaved store
    #pragma unroll
    for (int j=0;j<16;j++) SB[b][cl][ob+j] = f2bf(acc2[j]);
  }
  __syncthreads();
  // store CmsgT2 rows: wave w -> clauses w*4..w*4+3, lane covers (b, d-quad)
  {
    int bb = lane >> 4, h = lane & 15;
    #pragma unroll
    for (int t=0;t<4;t++){
      int cc = w*4 + t;
      ushort4 x;
      x.x = SB[bb][cc][4*h+0]; x.y = SB[bb][cc][4*h+1];
      x.z = SB[bb][cc][4*h+2]; x.w = SB[bb][cc][4*h+3];
      *(ushort4*)&CmsgT2[(size_t)(c0+cc)*256 + 4*lane] = x;
    }
  }
}

// ---- fused: literal side (blocks 0..511, 16 lits x 4 batches) + outC row sums ----
__global__ __launch_bounds__(512) void literal_redc_k(const float* __restrict__ Lt,
    const unsigned short* __restrict__ CmsgT2, const int* __restrict__ lcnt,
    const int* __restrict__ llist,
    const float* __restrict__ W_Lu, const float* __restrict__ b_Lu,
    float* __restrict__ outL, const float* __restrict__ outC, float* __restrict__ Csum){
  if (blockIdx.x >= 512){
    __shared__ float red[8];
    int r = blockIdx.x - 512;
    int t = threadIdx.x;
    float s = 0.f;
    const float4* p = (const float4*)(outC + (size_t)r*NCLS);
    #pragma unroll
    for (int i=0;i<8;i++){
      float4 v = p[t + 512*i];
      s += v.x + v.y + v.z + v.w;
    }
    #pragma unroll
    for (int sft=32;sft>0;sft>>=1) s += __shfl_xor(s, sft, 64);
    if ((t & 63) == 0) red[t >> 6] = s;
    __syncthreads();
    if (t == 0){
      float tot = 0.f;
      #pragma unroll
      for (int i=0;i<8;i++) tot += red[i];
      Csum[r] = tot;
    }
    return;
  }
  __shared__ float SX[4][64][17];
  __shared__ float SF[4][64][17];
  __shared__ float SM[4][16][65];
  int l0 = blockIdx.x << 4;
  int f0 = l0 ^ 4096;
  int lane = threadIdx.x & 63;
  int w = __builtin_amdgcn_readfirstlane(threadIdx.x >> 6);   // 0..7
  // stage L and flip(L): 256 rows (b,i) of 16 floats; wave w: rows w*32..+31, 4 rows/iter
  #pragma unroll
  for (int it=0; it<8; it++){
    int row = w*32 + it*4 + (lane>>4);
    int b = row >> 6, i = row & 63;
    int col = lane & 15;
    SX[b][i][col] = Lt[((size_t)b*64 + i)*NLIT + l0 + col];
    SF[b][i][col] = Lt[((size_t)b*64 + i)*NLIT + f0 + col];
  }
  // gather: wave w owns literals w*2, w*2+1
  {
    int kk[2], rT[2];
    #pragma unroll
    for (int t=0;t<2;t++){
      int k = lcnt[l0 + w*2 + t];
      kk[t] = k > LCAP ? LCAP : k;
      rT[t] = (kk[t]+3) >> 2;
    }
    int Rm = max(rT[0], rT[1]);
    float4 acc[2];
    #pragma unroll
    for (int t=0;t<2;t++) acc[t] = make_float4(0.f,0.f,0.f,0.f);
    for (int r=0;r<Rm;r++){
      #pragma unroll
      for (int t=0;t<2;t++){
        if (r < rT[t]){
          int4 li = *(const int4*)&llist[(l0 + w*2 + t)*LCAP + 4*r];
          int idx[4] = {li.x, li.y, li.z, li.w};
          #pragma unroll
          for (int e=0;e<4;e++){
            if (4*r+e < kk[t]){
              ushort4 x = *(const ushort4*)&CmsgT2[(size_t)idx[e]*256 + 4*lane];
              acc[t].x += bf2f(x.x); acc[t].y += bf2f(x.y);
              acc[t].z += bf2f(x.z); acc[t].w += bf2f(x.w);
            }
          }
        }
      }
    }
    int b = lane >> 4, h = lane & 15;
    #pragma unroll
    for (int t=0;t<2;t++){
      SM[b][w*2+t][4*h+0] = acc[t].x;
      SM[b][w*2+t][4*h+1] = acc[t].y;
      SM[b][w*2+t][4*h+2] = acc[t].z;
      SM[b][w*2+t][4*h+3] = acc[t].w;
    }
  }
  __syncthreads();
  // MLP: thread -> (b = w>>1, half = w&1, cl = lane&15, sub = lane>>4), 8 outputs
  int b = w >> 1, half = w & 1, cl = lane & 15, sub = lane >> 4;
  int ob = half*32 + sub*8;
  float acc[8];
  #pragma unroll
  for (int j=0;j<8;j++) acc[j] = b_Lu[ob+j];
  #pragma unroll 4
  for (int i=0;i<64;i++){
    float xx = SX[b][i][cl];
    float xm = SM[b][cl][i];
    float xf = SF[b][i][cl];
    #pragma unroll
    for (int j=0;j<8;j++){
      int o = ob + j;
      acc[j] += W_Lu[o*192+i]*xx + W_Lu[o*192+64+i]*xm + W_Lu[o*192+128+i]*xf;
    }
  }
  float* oL = outL + (size_t)b*DD*NLIT;
  #pragma unroll
  for (int j=0;j<8;j++) oL[(size_t)(ob+j)*NLIT + l0 + cl] = leaky(acc[j]);
}

// ---- outL row sums ----
__global__ __launch_bounds__(256) void redl_k(const float* __restrict__ outL,
    float* __restrict__ Lsum){
  __shared__ float red[4];
  int r = blockIdx.x;
  int t = threadIdx.x;
  float s = 0.f;
  const float4* p = (const float4*)(outL + (size_t)r*NLIT);
  #pragma unroll
  for (int i=0;i<8;i++){
    float4 v = p[t + 256*i];
    s += v.x + v.y + v.z + v.w;
  }
  #pragma unroll
  for (int sft=32;sft>0;sft>>=1) s += __shfl_xor(s, sft, 64);
  if ((t & 63) == 0) red[t >> 6] = s;
  __syncthreads();
  if (t == 0) Lsum[r] = red[0] + red[1] + red[2] + red[3];
}

// ---- global update ----
__global__ void u_k(const float* __restrict__ Lsum, const float* __restrict__ Csum,
                    const float* __restrict__ Ut, const float* __restrict__ W,
                    const float* __restrict__ bias, float* __restrict__ outU){
  int t = threadIdx.x;
  int b = t >> 6, o = t & 63;
  float acc = bias[o];
  for (int i=0;i<64;i++){
    acc += W[o*192+i]*Lsum[b*64+i] + W[o*192+64+i]*Csum[b*64+i] + W[o*192+128+i]*Ut[b*64+i];
  }
  outU[t] = leaky(acc);
}

extern "C" void kernel_launch(void* const* d_in, const int* in_sizes, int n_in,
                              void* d_out, int out_size, void* d_ws, size_t ws_size,
                              hipStream_t stream){
  (void)in_sizes; (void)n_in; (void)out_size; (void)ws_size;
  const float* L_t    = (const float*)d_in[0];
  const float* C_t    = (const float*)d_in[1];
  const float* U_t    = (const float*)d_in[2];
  const float* A      = (const float*)d_in[3];
  const float* W_Lmsg = (const float*)d_in[5];
  const float* b_Lmsg = (const float*)d_in[6];
  const float* W_Cmsg = (const float*)d_in[7];
  const float* b_Cmsg = (const float*)d_in[8];
  const float* W_Lu   = (const float*)d_in[9];
  const float* b_Lu   = (const float*)d_in[10];
  const float* W_Cu   = (const float*)d_in[11];
  const float* b_Cu   = (const float*)d_in[12];
  const float* W_Uu   = (const float*)d_in[13];
  const float* b_Uu   = (const float*)d_in[14];

  char* ws = (char*)d_ws;
  unsigned short* LmsgT2 = (unsigned short*)ws;             // [NLIT][4][64] bf16 = 4 MB
  unsigned short* CmsgT2 = (unsigned short*)(ws + 4194304); // [NCLS][4][64] bf16 = 8 MB
  int*   ccnt  = (int*)  (ws + 12582912);                   // 64 KB
  int*   lcnt  = (int*)  (ws + 12648448);                   // 32 KB
  float* Lsum  = (float*)(ws + 12681216);
  float* Csum  = (float*)(ws + 12682240);
  int*   clist = (int*)  (ws + 12683264);                   // 4 MB
  int*   llist = (int*)  (ws + 16877568);                   // 2 MB

  hipMemsetAsync(ws + 12582912, 0, 98304, stream);          // ccnt + lcnt

  float* outL = (float*)d_out;                       // [4,64,8192]
  float* outC = (float*)d_out + 2097152;             // [4,64,16384]
  float* outU = (float*)d_out + 6291456;             // [4,64,1]

  extract_lmsg_k<<<16896, 256, 0, stream>>>((const uint4*)A, ccnt, clist, lcnt, llist,
                                            L_t, W_Lmsg, b_Lmsg, LmsgT2);
  clause_k      <<<512,   512, 0, stream>>>(C_t, LmsgT2, ccnt, clist, W_Cu, b_Cu,
                                            W_Cmsg, b_Cmsg, CmsgT2, outC);
  literal_redc_k<<<768,   512, 0, stream>>>(L_t, CmsgT2, lcnt, llist, W_Lu, b_Lu,
                                            outL, outC, Csum);
  redl_k        <<<256,   256, 0, stream>>>(outL, Lsum);
  u_k           <<<1,     256, 0, stream>>>(Lsum, Csum, U_t, W_Uu, b_Uu, outU);
}

// Round 10
// 1051.565 us; speedup vs baseline: 1.0902x; 1.0902x over previous
//
#include <hip/hip_runtime.h>

#define NLIT 8192
#define NCLS 16384
#define DD 64
#define CCAP 64
#define LCAP 64

__device__ __forceinline__ float leaky(float x){ return x >= 0.f ? x : 0.01f*x; }

__device__ __forceinline__ int sel4(int g, int4 li){
  return g==0 ? li.x : (g==1 ? li.y : (g==2 ? li.z : li.w));
}

__device__ __forceinline__ float bf2f(unsigned short u){
  union { unsigned u; float f; } c; c.u = ((unsigned)u) << 16; return c.f;
}
__device__ __forceinline__ unsigned short f2bf(float f){
  union { float f; unsigned u; } c; c.f = f;
  unsigned b = c.u + 0x7fffu + ((c.u >> 16) & 1u);   // RNE
  return (unsigned short)(b >> 16);
}

// ---- fused: extract sparse lists from A  +  Lmsg linear (bf16 out) ----
__global__ __launch_bounds__(256) void extract_lmsg_k(const uint4* __restrict__ A4,
    int* __restrict__ ccnt, int* __restrict__ clist,
    int* __restrict__ lcnt, int* __restrict__ llist,
    const float* __restrict__ L, const float* __restrict__ W,
    const float* __restrict__ bias, unsigned short* __restrict__ LmsgT){
  if (blockIdx.x < 16384){
    const int T = 16384*256;
    int tid = blockIdx.x*256 + threadIdx.x;
    uint4 v[8];
    #pragma unroll
    for (int u=0;u<8;u++) v[u] = A4[tid + (size_t)u*T];
    #pragma unroll
    for (int u=0;u<8;u++){
      if (v[u].x | v[u].y | v[u].z | v[u].w){
        int i = tid + u*T;
        int c = i >> 11;
        int l = (i & 2047) << 2;
        unsigned vv[4] = {v[u].x, v[u].y, v[u].z, v[u].w};
        #pragma unroll
        for (int j=0;j<4;j++){
          if (vv[j]){
            int p = atomicAdd(&ccnt[c],1);
            if (p < CCAP) clist[c*CCAP+p] = l+j;
            int q = atomicAdd(&lcnt[l+j],1);
            if (q < LCAP) llist[(l+j)*LCAP+q] = c;
          }
        }
      }
    }
  } else {
    __shared__ float X[64][65];
    __shared__ float Y[64][65];
    int bid = blockIdx.x - 16384;                     // 0..511
    int b   = (bid & 7) >> 1;
    int l0  = (((bid >> 3) << 1) | (bid & 1)) << 6;
    int lane = threadIdx.x & 63;
    int wg = __builtin_amdgcn_readfirstlane(threadIdx.x >> 6);
    const float* Lb = L + (size_t)b*DD*NLIT;
    #pragma unroll
    for (int r=0;r<16;r++){
      int i = wg + 4*r;
      X[lane][i] = Lb[(size_t)i*NLIT + l0 + lane];
    }
    __syncthreads();
    float acc[16];
    #pragma unroll
    for (int j=0;j<16;j++) acc[j] = bias[wg*16+j];
    #pragma unroll 4
    for (int i=0;i<64;i++){
      float x = X[lane][i];
      #pragma unroll
      for (int j=0;j<16;j++) acc[j] += W[(wg*16+j)*64+i] * x;
    }
    #pragma unroll
    for (int j=0;j<16;j++) Y[lane][wg*16+j] = acc[j];
    __syncthreads();
    unsigned short* out = LmsgT + ((size_t)b*NLIT + l0)*64;
    #pragma unroll
    for (int r=0;r<16;r++){
      int cc = wg + 4*r;
      out[cc*64 + lane] = f2bf(Y[cc][lane]);
    }
  }
}

// grouped gather (bf16 payload): 8 nodes' chains interleaved in ONE uniform-trip
// loop -> 8 independent index loads + 32 payload loads in flight per round.
__device__ __forceinline__ void gather_grp8(const unsigned short* __restrict__ src,
    const int* __restrict__ list, int cap, const int* kk, int lane,
    float (* __restrict__ sb)[65], int row0){
  int g = lane >> 4;
  int h = lane & 15;
  float4 a[8];
  int rT[8];
  int Rm = 0;
  #pragma unroll
  for (int t=0;t<8;t++){
    a[t] = make_float4(0.f,0.f,0.f,0.f);
    rT[t] = (kk[t]+3) >> 2;
    Rm = max(Rm, rT[t]);
  }
  for (int r=0;r<Rm;r++){
    #pragma unroll
    for (int t=0;t<8;t++){
      if (r < rT[t]){
        int4 li = *(const int4*)&list[t*cap + 4*r];
        int e = 4*r + g;
        bool vd = e < kk[t];
        int idx = vd ? sel4(g, li) : 0;
        ushort4 x = *(const ushort4*)&src[(size_t)idx*64 + 4*h];
        if (vd){ a[t].x += bf2f(x.x); a[t].y += bf2f(x.y);
                 a[t].z += bf2f(x.z); a[t].w += bf2f(x.w); }
      }
    }
  }
  #pragma unroll
  for (int t=0;t<8;t++){
    #pragma unroll
    for (int s=16;s<=32;s<<=1){
      a[t].x += __shfl_xor(a[t].x, s, 64);
      a[t].y += __shfl_xor(a[t].y, s, 64);
      a[t].z += __shfl_xor(a[t].z, s, 64);
      a[t].w += __shfl_xor(a[t].w, s, 64);
    }
    float val = g==0 ? a[t].x : (g==1 ? a[t].y : (g==2 ? a[t].z : a[t].w));
    sb[row0+t][4*h+g] = val;
  }
}

// ---- clause side: 512 threads, bf16 message in/out ----
__global__ __launch_bounds__(512) void clause_k(const float* __restrict__ Ct,
    const unsigned short* __restrict__ LmsgT, const int* __restrict__ ccnt, const int* __restrict__ clist,
    const float* __restrict__ W_Cu, const float* __restrict__ b_Cu,
    const float* __restrict__ W_Cmsg, const float* __restrict__ b_Cmsg,
    unsigned short* __restrict__ CmsgT, float* __restrict__ outC){
  __shared__ float SA[64][65];
  __shared__ float SB[64][65];
  int bx = blockIdx.x;
  int b  = (bx & 7) >> 1;
  int c0 = (((bx >> 3) << 1) | (bx & 1)) << 6;
  int lane = threadIdx.x & 63;
  int wg = __builtin_amdgcn_readfirstlane(threadIdx.x >> 6);   // 0..7
  int kk[8];
  #pragma unroll
  for (int t=0;t<8;t++){
    int k = ccnt[c0 + wg*8 + t];
    kk[t] = k > CCAP ? CCAP : k;
  }
  const float* Cb = Ct + (size_t)b*DD*NCLS;
  #pragma unroll
  for (int r=0;r<8;r++){
    int i = wg + 8*r;
    SA[lane][i] = Cb[(size_t)i*NCLS + c0 + lane];
  }
  const unsigned short* Lm = LmsgT + (size_t)b*NLIT*64;
  gather_grp8(Lm, &clist[(c0+wg*8)*CCAP], CCAP, kk, lane, SB, wg*8);
  __syncthreads();
  float v[8];
  {
    float acc[8];
    #pragma unroll
    for (int j=0;j<8;j++) acc[j] = b_Cu[wg*8+j];
    #pragma unroll 4
    for (int i=0;i<64;i++){
      float xa = SA[lane][i];
      float xm = SB[lane][i];
      #pragma unroll
      for (int j=0;j<8;j++){
        int o = wg*8+j;
        acc[j] += W_Cu[o*128+i]*xa + W_Cu[o*128+64+i]*xm;
      }
    }
    #pragma unroll
    for (int j=0;j<8;j++) v[j] = leaky(acc[j]);
  }
  float* oC = outC + (size_t)b*DD*NCLS;
  #pragma unroll
  for (int j=0;j<8;j++){
    int o = wg*8+j;
    oC[(size_t)o*NCLS + c0 + lane] = v[j];
  }
  __syncthreads();
  #pragma unroll
  for (int j=0;j<8;j++) SB[lane][wg*8+j] = v[j];
  __syncthreads();
  float acc2[8];
  #pragma unroll
  for (int j=0;j<8;j++) acc2[j] = b_Cmsg[wg*8+j];
  #pragma unroll 4
  for (int i=0;i<64;i++){
    float x = SB[lane][i];
    #pragma unroll
    for (int j=0;j<8;j++) acc2[j] += W_Cmsg[(wg*8+j)*64+i]*x;
  }
  #pragma unroll
  for (int j=0;j<8;j++) SA[lane][wg*8+j] = acc2[j];
  __syncthreads();
  unsigned short* oM = CmsgT + ((size_t)b*NCLS + c0)*64;
  #pragma unroll
  for (int r=0;r<8;r++){
    int cc = wg + 8*r;
    oM[cc*64 + lane] = f2bf(SA[cc][lane]);
  }
}

// ---- fused: literal side (blocks 0..511)  +  outC row sums (512..767) ----
__global__ __launch_bounds__(512) void literal_redc_k(const float* __restrict__ Lt,
    const unsigned short* __restrict__ CmsgT, const int* __restrict__ lcnt, const int* __restrict__ llist,
    const float* __restrict__ W_Lu, const float* __restrict__ b_Lu,
    float* __restrict__ outL, const float* __restrict__ outC, float* __restrict__ Csum){
  if (blockIdx.x >= 512){
    __shared__ float red[8];
    int r = blockIdx.x - 512;
    int t = threadIdx.x;
    float s = 0.f;
    const float4* p = (const float4*)(outC + (size_t)r*NCLS);
    #pragma unroll
    for (int i=0;i<8;i++){
      float4 v = p[t + 512*i];
      s += v.x + v.y + v.z + v.w;
    }
    #pragma unroll
    for (int sft=32;sft>0;sft>>=1) s += __shfl_xor(s, sft, 64);
    if ((t & 63) == 0) red[t >> 6] = s;
    __syncthreads();
    if (t == 0){
      float tot = 0.f;
      #pragma unroll
      for (int i=0;i<8;i++) tot += red[i];
      Csum[r] = tot;
    }
    return;
  }
  __shared__ float SX[64][65];
  __shared__ float SF[64][65];
  __shared__ float SM[64][65];
  int bx = blockIdx.x;
  int b  = (bx & 7) >> 1;
  int l0 = (((bx >> 3) << 1) | (bx & 1)) << 6;
  int lane = threadIdx.x & 63;
  int wg = __builtin_amdgcn_readfirstlane(threadIdx.x >> 6);   // 0..7
  int kk[8];
  #pragma unroll
  for (int t=0;t<8;t++){
    int k = lcnt[l0 + wg*8 + t];
    kk[t] = k > LCAP ? LCAP : k;
  }
  const float* Lb = Lt + (size_t)b*DD*NLIT;
  int f0 = l0 ^ 4096;
  #pragma unroll
  for (int r=0;r<8;r++){
    int i = wg + 8*r;
    SX[lane][i] = Lb[(size_t)i*NLIT + l0 + lane];
    SF[lane][i] = Lb[(size_t)i*NLIT + f0 + lane];
  }
  const unsigned short* Cm = CmsgT + (size_t)b*NCLS*64;
  gather_grp8(Cm, &llist[(l0+wg*8)*LCAP], LCAP, kk, lane, SM, wg*8);
  __syncthreads();
  float acc[8];
  #pragma unroll
  for (int j=0;j<8;j++) acc[j] = b_Lu[wg*8+j];
  #pragma unroll 4
  for (int i=0;i<64;i++){
    float xx = SX[lane][i], xm = SM[lane][i], xf = SF[lane][i];
    #pragma unroll
    for (int j=0;j<8;j++){
      int o = wg*8+j;
      acc[j] += W_Lu[o*192+i]*xx + W_Lu[o*192+64+i]*xm + W_Lu[o*192+128+i]*xf;
    }
  }
  float* oL = outL + (size_t)b*DD*NLIT;
  #pragma unroll
  for (int j=0;j<8;j++){
    int o = wg*8+j;
    oL[(size_t)o*NLIT + l0 + lane] = leaky(acc[j]);
  }
}

// ---- outL row sums ----
__global__ __launch_bounds__(256) void redl_k(const float* __restrict__ outL,
    float* __restrict__ Lsum){
  __shared__ float red[4];
  int r = blockIdx.x;
  int t = threadIdx.x;
  float s = 0.f;
  const float4* p = (const float4*)(outL + (size_t)r*NLIT);
  #pragma unroll
  for (int i=0;i<8;i++){
    float4 v = p[t + 256*i];
    s += v.x + v.y + v.z + v.w;
  }
  #pragma unroll
  for (int sft=32;sft>0;sft>>=1) s += __shfl_xor(s, sft, 64);
  if ((t & 63) == 0) red[t >> 6] = s;
  __syncthreads();
  if (t == 0) Lsum[r] = red[0] + red[1] + red[2] + red[3];
}

// ---- global update ----
__global__ void u_k(const float* __restrict__ Lsum, const float* __restrict__ Csum,
                    const float* __restrict__ Ut, const float* __restrict__ W,
                    const float* __restrict__ bias, float* __restrict__ outU){
  int t = threadIdx.x;
  int b = t >> 6, o = t & 63;
  float acc = bias[o];
  for (int i=0;i<64;i++){
    acc += W[o*192+i]*Lsum[b*64+i] + W[o*192+64+i]*Csum[b*64+i] + W[o*192+128+i]*Ut[b*64+i];
  }
  outU[t] = leaky(acc);
}

extern "C" void kernel_launch(void* const* d_in, const int* in_sizes, int n_in,
                              void* d_out, int out_size, void* d_ws, size_t ws_size,
                              hipStream_t stream){
  (void)in_sizes; (void)n_in; (void)out_size; (void)ws_size;
  const float* L_t    = (const float*)d_in[0];
  const float* C_t    = (const float*)d_in[1];
  const float* U_t    = (const float*)d_in[2];
  const float* A      = (const float*)d_in[3];
  const float* W_Lmsg = (const float*)d_in[5];
  const float* b_Lmsg = (const float*)d_in[6];
  const float* W_Cmsg = (const float*)d_in[7];
  const float* b_Cmsg = (const float*)d_in[8];
  const float* W_Lu   = (const float*)d_in[9];
  const float* b_Lu   = (const float*)d_in[10];
  const float* W_Cu   = (const float*)d_in[11];
  const float* b_Cu   = (const float*)d_in[12];
  const float* W_Uu   = (const float*)d_in[13];
  const float* b_Uu   = (const float*)d_in[14];

  char* ws = (char*)d_ws;
  unsigned short* LmsgT = (unsigned short*)ws;             // 4 MB
  unsigned short* CmsgT = (unsigned short*)(ws + 4194304); // 8 MB
  int*   ccnt  = (int*)  (ws + 12582912);                  // 64 KB
  int*   lcnt  = (int*)  (ws + 12648448);                  // 32 KB
  float* Lsum  = (float*)(ws + 12681216);
  float* Csum  = (float*)(ws + 12682240);
  int*   clist = (int*)  (ws + 12683264);                  // 4 MB
  int*   llist = (int*)  (ws + 16877568);                  // 2 MB

  hipMemsetAsync(ws + 12582912, 0, 98304, stream);         // ccnt + lcnt

  float* outL = (float*)d_out;                       // [4,64,8192]
  float* outC = (float*)d_out + 2097152;             // [4,64,16384]
  float* outU = (float*)d_out + 6291456;             // [4,64,1]

  extract_lmsg_k<<<16896, 256, 0, stream>>>((const uint4*)A, ccnt, clist, lcnt, llist,
                                            L_t, W_Lmsg, b_Lmsg, LmsgT);
  clause_k      <<<1024,  512, 0, stream>>>(C_t, LmsgT, ccnt, clist, W_Cu, b_Cu,
                                            W_Cmsg, b_Cmsg, CmsgT, outC);
  literal_redc_k<<<768,   512, 0, stream>>>(L_t, CmsgT, lcnt, llist, W_Lu, b_Lu,
                                            outL, outC, Csum);
  redl_k        <<<256,   256, 0, stream>>>(outL, Lsum);
  u_k           <<<1,     256, 0, stream>>>(Lsum, Csum, U_t, W_Uu, b_Uu, outU);
}